// Round 5
// baseline (298.084 us; speedup 1.0000x reference)
//
#include <hip/hip_runtime.h>
#include <hip/hip_bf16.h>

#define EPS 1e-5f

typedef short bf16x8 __attribute__((ext_vector_type(8)));
typedef float f32x4 __attribute__((ext_vector_type(4)));

#define GL16(gp, lp) __builtin_amdgcn_global_load_lds( \
    (const __attribute__((address_space(1))) void*)(gp), \
    (__attribute__((address_space(3))) void*)(lp), 16, 0, 0)

__device__ __forceinline__ unsigned short f2bf(float f) {
  union { float f; unsigned u; } v; v.f = f;
  return (unsigned short)((v.u + 0x7FFFu + ((v.u >> 16) & 1u)) >> 16);
}

// ---------------- 4 weight transposes (K x N fp32 -> N x K bf16) in one launch ----------------
__global__ void wtrans4_kernel(const float* __restrict__ W0, const float* __restrict__ W1,
                               const float* __restrict__ W2, const float* __restrict__ W3,
                               unsigned short* __restrict__ T0, unsigned short* __restrict__ T1,
                               unsigned short* __restrict__ T2, unsigned short* __restrict__ T3) {
  __shared__ float tile[32][33];
  int z = blockIdx.z;
  const float* W = z == 0 ? W0 : z == 1 ? W1 : z == 2 ? W2 : W3;
  unsigned short* Wt = z == 0 ? T0 : z == 1 ? T1 : z == 2 ? T2 : T3;
  float scale = (z == 0) ? 0.125f : 1.0f;   // fold 1/sqrt(64) into Wq
  int n0 = blockIdx.x * 32, k0 = blockIdx.y * 32;
  int c = threadIdx.x & 31, r0 = threadIdx.x >> 5;
  #pragma unroll
  for (int rr = 0; rr < 32; rr += 8)
    tile[r0 + rr][c] = W[(k0 + r0 + rr) * 512 + n0 + c];
  __syncthreads();
  #pragma unroll
  for (int rr = 0; rr < 32; rr += 8)
    Wt[(n0 + r0 + rr) * 512 + k0 + c] = f2bf(tile[c][r0 + rr] * scale);
}

// ---------------- per-(b,q) stoich row stats ----------------
__global__ void frac_stats_kernel(const float* __restrict__ frac,
                                  float* __restrict__ fstats) {
  int wid = (int)((blockIdx.x * blockDim.x + threadIdx.x) >> 6);
  int ln = threadIdx.x & 63;
  if (wid >= 8192) return;
  int b = wid >> 10, q = wid & 1023;
  const float* fr = frac + b * 1024;
  float fq = fr[q];
  float sp = 0.f, sn = 0.f, sp2 = 0.f, sn2 = 0.f;
  for (int i = ln; i < 1024; i += 64) {
    float f = fr[i];
    float dm = (f - fq) * (fq * f);
    float p = fmaxf(dm, 0.f), nn = fminf(dm, 0.f);
    sp += p; sn += nn; sp2 += p * p; sn2 += nn * nn;
  }
  #pragma unroll
  for (int m = 32; m; m >>= 1) {
    sp += __shfl_xor(sp, m); sn += __shfl_xor(sn, m);
    sp2 += __shfl_xor(sp2, m); sn2 += __shfl_xor(sn2, m);
  }
  if (ln == 0) {
    float4 o; o.x = sp; o.y = sn; o.z = sp2; o.w = sn2;
    *(float4*)(fstats + (size_t)wid * 4) = o;
  }
}

// ---------------- fused QKV GEMM: fp32 A reg-staged -> bf16 LDS; one launch, z = {q,k,v} ----------------
__global__ __launch_bounds__(256) void qkv_gemm_kernel(
    const float* __restrict__ Aq, const float* __restrict__ Ak, const float* __restrict__ Av,
    const unsigned short* __restrict__ WqT, const unsigned short* __restrict__ WkT,
    const unsigned short* __restrict__ WvT,
    const float* __restrict__ bq, const float* __restrict__ bk, const float* __restrict__ bv,
    unsigned short* __restrict__ Qh, unsigned short* __restrict__ Kh,
    unsigned short* __restrict__ Vt) {
  __shared__ unsigned short Al[2][128 * 32];
  __shared__ unsigned short Bl[2][128 * 32];
  const int z = blockIdx.z;
  const float* A = z == 0 ? Aq : z == 1 ? Ak : Av;
  const unsigned short* Bt = z == 0 ? WqT : z == 1 ? WkT : WvT;
  const float* bias = z == 0 ? bq : z == 1 ? bk : bv;
  const float bscale = (z == 0) ? 0.125f : 1.0f;

  const int tid = threadIdx.x, ln = tid & 63, wv = tid >> 6;
  const int m0 = blockIdx.y * 128, n0 = blockIdx.x * 128;
  const int wr = wv >> 1, wc = wv & 1;

  const int arow = tid >> 1;            // 0..127
  const int agh = (tid & 1) * 2;        // first of 2 granules (16B bf16 = 8 elems)

  auto stageB = [&](int kt, int buf) {
    int kb = kt * 32;
    #pragma unroll
    for (int u = 0; u < 2; ++u) {
      int n = tid + u * 256;
      int Lrow = n >> 2, kcs = n & 3;
      int kc = kcs ^ (Lrow & 3);
      GL16(Bt + (size_t)(n0 + Lrow) * 512 + kb + kc * 8, &Bl[buf][n * 8]);
    }
  };
  auto loadA = [&](int kt, float4* la) {
    const float* src = A + (size_t)(m0 + arow) * 512 + kt * 32 + agh * 8;
    la[0] = *(const float4*)(src);
    la[1] = *(const float4*)(src + 4);
    la[2] = *(const float4*)(src + 8);
    la[3] = *(const float4*)(src + 12);
  };
  auto writeA = [&](int buf, const float4* la) {
    #pragma unroll
    for (int G = 0; G < 2; ++G) {
      union { bf16x8 v; unsigned short u[8]; } pk;
      float4 a = la[2 * G], b2 = la[2 * G + 1];
      pk.u[0] = f2bf(a.x); pk.u[1] = f2bf(a.y); pk.u[2] = f2bf(a.z); pk.u[3] = f2bf(a.w);
      pk.u[4] = f2bf(b2.x); pk.u[5] = f2bf(b2.y); pk.u[6] = f2bf(b2.z); pk.u[7] = f2bf(b2.w);
      int dg = (agh + G) ^ (arow & 3);   // swizzled LDS granule
      *(bf16x8*)(&Al[buf][arow * 32 + dg * 8]) = pk.v;
    }
  };

  f32x4 acc[4][4] = {};
  float4 la[4];
  loadA(0, la); writeA(0, la);
  stageB(0, 0);
  for (int kt = 0; kt < 16; ++kt) {
    __syncthreads();
    if (kt < 15) { loadA(kt + 1, la); stageB(kt + 1, (kt + 1) & 1); }
    const unsigned short* a_ = Al[kt & 1];
    const unsigned short* b_ = Bl[kt & 1];
    const int kc = ln >> 4;
    bf16x8 afr[4], bfr[4];
    #pragma unroll
    for (int m = 0; m < 4; ++m) {
      int r = wr * 64 + m * 16 + (ln & 15);
      afr[m] = *(const bf16x8*)(a_ + r * 32 + ((kc ^ (r & 3)) * 8));
    }
    #pragma unroll
    for (int n = 0; n < 4; ++n) {
      int r = wc * 64 + n * 16 + (ln & 15);
      bfr[n] = *(const bf16x8*)(b_ + r * 32 + ((kc ^ (r & 3)) * 8));
    }
    #pragma unroll
    for (int m = 0; m < 4; ++m)
      #pragma unroll
      for (int n = 0; n < 4; ++n)
        acc[m][n] = __builtin_amdgcn_mfma_f32_16x16x32_bf16(afr[m], bfr[n], acc[m][n], 0, 0, 0);
    if (kt < 15) writeA((kt + 1) & 1, la);   // vmcnt wait lands after MFMAs
  }

  #pragma unroll
  for (int m = 0; m < 4; ++m) {
    #pragma unroll
    for (int n = 0; n < 4; ++n) {
      int gm0 = m0 + wr * 64 + m * 16 + (ln >> 4) * 4;
      int gn = n0 + wc * 64 + n * 16 + (ln & 15);
      float bvv = bias[gn] * bscale;
      int hh = gn >> 6, d = gn & 63;
      if (z < 2) {  // Q/K -> (b,h,t,d)
        unsigned short* o = z == 0 ? Qh : Kh;
        #pragma unroll
        for (int i = 0; i < 4; ++i) {
          int gm = gm0 + i;
          int bb = gm >> 10, t = gm & 1023;
          o[(size_t)((bb * 8 + hh) * 1024 + t) * 64 + d] = f2bf(acc[m][n][i] + bvv);
        }
      } else {      // V -> (b,h,d,t)
        int bb = gm0 >> 10, t = gm0 & 1023;
        ushort4 pk;
        pk.x = f2bf(acc[m][n][0] + bvv);
        pk.y = f2bf(acc[m][n][1] + bvv);
        pk.z = f2bf(acc[m][n][2] + bvv);
        pk.w = f2bf(acc[m][n][3] + bvv);
        *(ushort4*)(Vt + (size_t)((bb * 8 + hh) * 64 + d) * 1024 + t) = pk;
      }
    }
  }
}

// ---------------- final GEMM: bf16 A via GL16, fp32 out ----------------
__global__ __launch_bounds__(256) void gemm_out_kernel(
    const unsigned short* __restrict__ A,
    const unsigned short* __restrict__ Bt,
    const float* __restrict__ bias,
    float* __restrict__ out) {
  __shared__ unsigned short Al[2][128 * 32];
  __shared__ unsigned short Bl[2][128 * 32];
  const int tid = threadIdx.x, ln = tid & 63, wv = tid >> 6;
  const int m0 = blockIdx.y * 128, n0 = blockIdx.x * 128;
  const int wr = wv >> 1, wc = wv & 1;

  auto stage = [&](int kt, int buf) {
    int kb = kt * 32;
    #pragma unroll
    for (int u = 0; u < 2; ++u) {
      int n = tid + u * 256;
      int Lrow = n >> 2, kcs = n & 3;
      int kc = kcs ^ (Lrow & 3);
      GL16(A + (size_t)(m0 + Lrow) * 512 + kb + kc * 8, &Al[buf][n * 8]);
      GL16(Bt + (size_t)(n0 + Lrow) * 512 + kb + kc * 8, &Bl[buf][n * 8]);
    }
  };

  f32x4 acc[4][4] = {};
  stage(0, 0);
  for (int kt = 0; kt < 16; ++kt) {
    __syncthreads();
    if (kt < 15) stage(kt + 1, (kt + 1) & 1);
    const unsigned short* a_ = Al[kt & 1];
    const unsigned short* b_ = Bl[kt & 1];
    const int kc = ln >> 4;
    bf16x8 afr[4], bfr[4];
    #pragma unroll
    for (int m = 0; m < 4; ++m) {
      int r = wr * 64 + m * 16 + (ln & 15);
      afr[m] = *(const bf16x8*)(a_ + r * 32 + ((kc ^ (r & 3)) * 8));
    }
    #pragma unroll
    for (int n = 0; n < 4; ++n) {
      int r = wc * 64 + n * 16 + (ln & 15);
      bfr[n] = *(const bf16x8*)(b_ + r * 32 + ((kc ^ (r & 3)) * 8));
    }
    #pragma unroll
    for (int m = 0; m < 4; ++m)
      #pragma unroll
      for (int n = 0; n < 4; ++n)
        acc[m][n] = __builtin_amdgcn_mfma_f32_16x16x32_bf16(afr[m], bfr[n], acc[m][n], 0, 0, 0);
  }
  #pragma unroll
  for (int m = 0; m < 4; ++m)
    #pragma unroll
    for (int n = 0; n < 4; ++n) {
      int gm0 = m0 + wr * 64 + m * 16 + (ln >> 4) * 4;
      int gn = n0 + wc * 64 + n * 16 + (ln & 15);
      float bvv = bias[gn];
      #pragma unroll
      for (int i = 0; i < 4; ++i)
        out[(size_t)(gm0 + i) * 512 + gn] = acc[m][n][i] + bvv;
    }
}

// ---------------- fused attention v5: K via LDS, S register-resident, V prefetched ----------------
__global__ __launch_bounds__(512) void attn_kernel(
    const unsigned short* __restrict__ Qh,   // (b,h,t,d) bf16, pre-scaled by 1/8
    const unsigned short* __restrict__ Kh,   // (b,h,t,d) bf16
    const unsigned short* __restrict__ Vt,   // (b,h,d,t) bf16
    unsigned short* __restrict__ attnO,      // (b,t,h*64+d) bf16
    const float* __restrict__ frac,
    const float* __restrict__ fstats,
    const float* __restrict__ alpha_pos,
    const float* __restrict__ alpha_neg,
    const float* __restrict__ gamma_p,
    const float* __restrict__ delta_p,
    const int* __restrict__ afb_p) {
  __shared__ unsigned short Kl[2][128 * 64];   // 2 x 16KB, swizzled
  __shared__ float Obuf[32][64];               // 8KB
  __shared__ float sumW[8][32];
  __shared__ float sumW2[8][32];
  __shared__ float sumP[8][32];
  __shared__ __align__(16) float fk[1024];
  __shared__ float4 rowc[32];
  __shared__ float rowSh[32];
  __shared__ float rowRcp[32];

  const int L = blockIdx.x;
  const int slot = L >> 3;
  const int bh = (L & 7) + 8 * (slot >> 5);    // XCD-aware remap
  const int t0 = (slot & 31) * 32;
  const int b = bh >> 3, h = bh & 7;

  const int tid = threadIdx.x, ln = tid & 63, wv = tid >> 6;
  const int c = ln & 15, g = ln >> 4;

  fk[tid] = frac[b * 1024 + tid];
  fk[tid + 512] = frac[b * 1024 + 512 + tid];
  {
    float* ob = &Obuf[0][0];
    ob[tid] = 0.f; ob[tid + 512] = 0.f; ob[tid + 1024] = 0.f; ob[tid + 1536] = 0.f;
  }

  // Q B-fragments
  bf16x8 qf[2][2];
  #pragma unroll
  for (int qt = 0; qt < 2; ++qt) {
    const unsigned short* qrow = Qh + (size_t)(bh * 1024 + t0 + qt * 16 + c) * 64 + g * 8;
    qf[qt][0] = *(const bf16x8*)(qrow);
    qf[qt][1] = *(const bf16x8*)(qrow + 32);
  }

  auto stageK = [&](int kt, int buf) {
    #pragma unroll
    for (int u = 0; u < 2; ++u) {
      int n = tid + u * 512;
      int row = n >> 3, kc = (n & 7) ^ (row & 7);   // source-side chunk swizzle
      GL16(Kh + (size_t)(bh * 1024 + kt * 128 + row) * 64 + kc * 8,
           &Kl[buf][n * 8]);
    }
  };

  // ---- phase 1: QK^T, 8 x 128-key LDS tiles, S register-resident ----
  // lane(c,g) S[kt][qt][r] = score[key = kt*128 + wv*16 + g*4 + r][q = t0 + qt*16 + c]
  stageK(0, 0);
  f32x4 S[8][2];
  const int krow = wv * 16 + c;
  #pragma unroll
  for (int kt = 0; kt < 8; ++kt) {
    __syncthreads();
    if (kt < 7) stageK(kt + 1, (kt + 1) & 1);
    const unsigned short* kb_ = Kl[kt & 1];
    int kc0 = (g ^ (krow & 7)) * 8;
    int kc1 = ((g + 4) ^ (krow & 7)) * 8;
    bf16x8 kf0 = *(const bf16x8*)(kb_ + krow * 64 + kc0);
    bf16x8 kf1 = *(const bf16x8*)(kb_ + krow * 64 + kc1);
    #pragma unroll
    for (int qt = 0; qt < 2; ++qt) {
      f32x4 a = {0.f, 0.f, 0.f, 0.f};
      a = __builtin_amdgcn_mfma_f32_16x16x32_bf16(kf0, qf[qt][0], a, 0, 0, 0);
      a = __builtin_amdgcn_mfma_f32_16x16x32_bf16(kf1, qf[qt][1], a, 0, 0, 0);
      S[kt][qt] = a;
    }
  }

  // ---- phase 2: logits row stats ----
  {
    float sL[2] = {0.f, 0.f}, sL2[2] = {0.f, 0.f};
    #pragma unroll
    for (int kt = 0; kt < 8; ++kt)
      #pragma unroll
      for (int qt = 0; qt < 2; ++qt)
        #pragma unroll
        for (int r = 0; r < 4; ++r) {
          float v = S[kt][qt][r];
          sL[qt] += v; sL2[qt] += v * v;
        }
    #pragma unroll
    for (int qt = 0; qt < 2; ++qt) {
      sL[qt] += __shfl_xor(sL[qt], 16);
      sL[qt] += __shfl_xor(sL[qt], 32);
      sL2[qt] += __shfl_xor(sL2[qt], 16);
      sL2[qt] += __shfl_xor(sL2[qt], 32);
      if (g == 0) { sumW[wv][qt * 16 + c] = sL[qt]; sumW2[wv][qt * 16 + c] = sL2[qt]; }
    }
  }
  __syncthreads();
  if (tid < 32) {
    float sl = 0.f, sl2 = 0.f;
    #pragma unroll
    for (int w = 0; w < 8; ++w) { sl += sumW[w][tid]; sl2 += sumW2[w][tid]; }
    float mul_ = sl * (1.f / 1024.f);
    float varl = fmaxf((sl2 - 1024.f * mul_ * mul_) * (1.f / 1023.f), 0.f);
    float cA = (*gamma_p) / (sqrtf(varl) + EPS);
    float ap = alpha_pos[h], an = alpha_neg[h];
    float4 st = *(const float4*)(fstats + (size_t)(b * 1024 + t0 + tid) * 4);
    float msum = ap * st.x + an * st.y;
    float msq = ap * ap * st.z + an * an * st.w;
    float mus = msum * (1.f / 1024.f);
    float vars = fmaxf((msq - 1024.f * mus * mus) * (1.f / 1023.f), 0.f);
    float cB = (*afb_p) ? ((*delta_p) / (sqrtf(vars) + EPS)) : 0.f;
    const float L2E = 1.4426950408889634f;
    float a_ = 0.5f * (ap + an), c_ = 0.5f * (ap - an);
    float4 rc;
    rc.x = frac[b * 1024 + t0 + tid];   // fq
    rc.y = cA * L2E;                    // logits coef (exp2 domain)
    rc.z = cB * a_ * L2E;               // x coef
    rc.w = cB * c_ * L2E;               // |x| coef
    rowc[tid] = rc;
    rowSh[tid] = (cA * mul_ + cB * mus) * L2E;
  }
  __syncthreads();

  // ---- prefetch V for dt=0,1 (consumed after exp; latency hidden under VALU) ----
  union BV { ushort4 s[2]; bf16x8 v; };
  BV v0[4], v1[4];
  {
    const unsigned short* vr0 = Vt + (size_t)(bh * 64 + 0 * 16 + c) * 1024 + wv * 16 + g * 4;
    const unsigned short* vr1 = Vt + (size_t)(bh * 64 + 1 * 16 + c) * 1024 + wv * 16 + g * 4;
    #pragma unroll
    for (int p = 0; p < 4; ++p) {
      v0[p].s[0] = *(const ushort4*)(vr0 + p * 256);
      v0[p].s[1] = *(const ushort4*)(vr0 + p * 256 + 128);
      v1[p].s[0] = *(const ushort4*)(vr1 + p * 256);
      v1[p].s[1] = *(const ushort4*)(vr1 + p * 256 + 128);
    }
  }

  // ---- phase 3: exp2 transform in registers (overwrite S), psum ----
  {
    const float4 rc0 = rowc[c], rc1 = rowc[16 + c];
    const float sh0 = rowSh[c], sh1 = rowSh[16 + c];
    float ps0 = 0.f, ps1 = 0.f;
    #pragma unroll
    for (int kt = 0; kt < 8; ++kt) {
      float4 f4 = *(const float4*)(&fk[kt * 128 + wv * 16 + g * 4]);
      float fr[4] = {f4.x, f4.y, f4.z, f4.w};
      #pragma unroll
      for (int r = 0; r < 4; ++r) {
        float f = fr[r];
        {
          float t = f * rc0.x, d = f - rc0.x;
          float x = t * d, ax = t * __builtin_fabsf(d);
          float arg = rc0.y * S[kt][0][r] + rc0.z * x + rc0.w * ax - sh0;
          float e = __builtin_amdgcn_exp2f(arg);
          ps0 += e; S[kt][0][r] = e;
        }
        {
          float t = f * rc1.x, d = f - rc1.x;
          float x = t * d, ax = t * __builtin_fabsf(d);
          float arg = rc1.y * S[kt][1][r] + rc1.z * x + rc1.w * ax - sh1;
          float e = __builtin_amdgcn_exp2f(arg);
          ps1 += e; S[kt][1][r] = e;
        }
      }
    }
    ps0 += __shfl_xor(ps0, 16); ps0 += __shfl_xor(ps0, 32);
    ps1 += __shfl_xor(ps1, 16); ps1 += __shfl_xor(ps1, 32);
    if (g == 0) { sumP[wv][c] = ps0; sumP[wv][16 + c] = ps1; }
  }

  // ---- pack P A-fragments (round-half-up bf16) ----
  // frag p dword m: keys kt = 2p + (m>>1), r = 2*(m&1), r+1
  union AW { unsigned u[4]; bf16x8 v; };
  AW aw[2][4];
  #pragma unroll
  for (int qt = 0; qt < 2; ++qt)
    #pragma unroll
    for (int p = 0; p < 4; ++p)
      #pragma unroll
      for (int m = 0; m < 4; ++m) {
        int kt = 2 * p + (m >> 1), r0 = (m & 1) * 2;
        unsigned u0 = __float_as_uint(S[kt][qt][r0]);
        unsigned u1 = __float_as_uint(S[kt][qt][r0 + 1]);
        aw[qt][p].u[m] = ((u1 + 0x8000u) & 0xFFFF0000u) | ((u0 + 0x8000u) >> 16);
      }

  // ---- phase 4: PV, V dt-tiles prefetched in rotation ----
  auto loadV = [&](BV* dst, int dt) {
    const unsigned short* vr = Vt + (size_t)(bh * 64 + dt * 16 + c) * 1024 + wv * 16 + g * 4;
    #pragma unroll
    for (int p = 0; p < 4; ++p) {
      dst[p].s[0] = *(const ushort4*)(vr + p * 256);
      dst[p].s[1] = *(const ushort4*)(vr + p * 256 + 128);
    }
  };
  auto pvStep = [&](int dt, const BV* vv) {
    #pragma unroll
    for (int qt = 0; qt < 2; ++qt) {
      f32x4 o = {0.f, 0.f, 0.f, 0.f};
      #pragma unroll
      for (int p = 0; p < 4; ++p)
        o = __builtin_amdgcn_mfma_f32_16x16x32_bf16(aw[qt][p].v, vv[p].v, o, 0, 0, 0);
      #pragma unroll
      for (int r = 0; r < 4; ++r)
        atomicAdd(&Obuf[qt * 16 + g * 4 + r][dt * 16 + c], o[r]);
    }
  };
  pvStep(0, v0);
  loadV(v0, 2);
  pvStep(1, v1);
  loadV(v1, 3);
  pvStep(2, v0);
  pvStep(3, v1);

  __syncthreads();
  if (tid < 32) {
    float s = 0.f;
    #pragma unroll
    for (int w = 0; w < 8; ++w) s += sumP[w][tid];
    rowRcp[tid] = 1.f / s;
  }
  __syncthreads();

  // ---- epilogue ----
  {
    int qi = tid >> 4, d0 = (tid & 15) * 4;
    float rcp = rowRcp[qi];
    float4 ov = *(const float4*)&Obuf[qi][d0];
    ushort4 pk;
    pk.x = f2bf(ov.x * rcp); pk.y = f2bf(ov.y * rcp);
    pk.z = f2bf(ov.z * rcp); pk.w = f2bf(ov.w * rcp);
    *(ushort4*)(attnO + (size_t)(b * 1024 + t0 + qi) * 512 + h * 64 + d0) = pk;
  }
}

extern "C" void kernel_launch(void* const* d_in, const int* in_sizes, int n_in,
                              void* d_out, int out_size, void* d_ws, size_t ws_size,
                              hipStream_t stream) {
  const float* q = (const float*)d_in[0];
  const float* k = (const float*)d_in[1];
  const float* v = (const float*)d_in[2];
  const float* frac = (const float*)d_in[3];
  const float* Wq = (const float*)d_in[4];
  const float* bq = (const float*)d_in[5];
  const float* Wk = (const float*)d_in[6];
  const float* bk = (const float*)d_in[7];
  const float* Wv = (const float*)d_in[8];
  const float* bv = (const float*)d_in[9];
  const float* Wo = (const float*)d_in[10];
  const float* bo = (const float*)d_in[11];
  const float* ap = (const float*)d_in[12];
  const float* an = (const float*)d_in[13];
  const float* gm = (const float*)d_in[14];
  const float* dl = (const float*)d_in[15];
  const int* afb = (const int*)d_in[16];

  char* ws = (char*)d_ws;
  unsigned short* wqT = (unsigned short*)(ws + 25165824);
  unsigned short* wkT = (unsigned short*)(ws + 25690112);
  unsigned short* wvT = (unsigned short*)(ws + 26214400);
  unsigned short* woT = (unsigned short*)(ws + 26738688);
  unsigned short* Qh = (unsigned short*)(ws + 27262976);
  unsigned short* Kh = (unsigned short*)(ws + 35651584);
  unsigned short* Vt = (unsigned short*)(ws + 44040192);
  unsigned short* aO = (unsigned short*)(ws + 52428800);
  float* fst = (float*)(ws + 60817408);

  wtrans4_kernel<<<dim3(16, 16, 4), 256, 0, stream>>>(Wq, Wk, Wv, Wo, wqT, wkT, wvT, woT);
  frac_stats_kernel<<<2048, 256, 0, stream>>>(frac, fst);
  qkv_gemm_kernel<<<dim3(4, 64, 3), 256, 0, stream>>>(q, k, v, wqT, wkT, wvT,
                                                      bq, bk, bv, Qh, Kh, Vt);
  attn_kernel<<<dim3(2048), 512, 0, stream>>>(Qh, Kh, Vt, aO, frac, fst,
                                              ap, an, gm, dl, afb);
  gemm_out_kernel<<<dim3(4, 64), 256, 0, stream>>>(aO, woT, bo, (float*)d_out);
}

// Round 6
// 233.016 us; speedup vs baseline: 1.2792x; 1.2792x over previous
//
#include <hip/hip_runtime.h>
#include <hip/hip_bf16.h>

#define EPS 1e-5f

typedef short bf16x8 __attribute__((ext_vector_type(8)));
typedef float f32x4 __attribute__((ext_vector_type(4)));

#define GL16(gp, lp) __builtin_amdgcn_global_load_lds( \
    (const __attribute__((address_space(1))) void*)(gp), \
    (__attribute__((address_space(3))) void*)(lp), 16, 0, 0)

__device__ __forceinline__ unsigned short f2bf(float f) {
  union { float f; unsigned u; } v; v.f = f;
  return (unsigned short)((v.u + 0x7FFFu + ((v.u >> 16) & 1u)) >> 16);
}

// ---------------- 4 weight transposes (K x N fp32 -> N x K bf16) ----------------
__global__ void wtrans4_kernel(const float* __restrict__ W0, const float* __restrict__ W1,
                               const float* __restrict__ W2, const float* __restrict__ W3,
                               unsigned short* __restrict__ T0, unsigned short* __restrict__ T1,
                               unsigned short* __restrict__ T2, unsigned short* __restrict__ T3) {
  __shared__ float tile[32][33];
  int z = blockIdx.z;
  const float* W = z == 0 ? W0 : z == 1 ? W1 : z == 2 ? W2 : W3;
  unsigned short* Wt = z == 0 ? T0 : z == 1 ? T1 : z == 2 ? T2 : T3;
  float scale = (z == 0) ? 0.125f : 1.0f;
  int n0 = blockIdx.x * 32, k0 = blockIdx.y * 32;
  int c = threadIdx.x & 31, r0 = threadIdx.x >> 5;
  #pragma unroll
  for (int rr = 0; rr < 32; rr += 8)
    tile[r0 + rr][c] = W[(k0 + r0 + rr) * 512 + n0 + c];
  __syncthreads();
  #pragma unroll
  for (int rr = 0; rr < 32; rr += 8)
    Wt[(n0 + r0 + rr) * 512 + k0 + c] = f2bf(tile[c][r0 + rr] * scale);
}

// ---------------- per-(b,q) stoich row stats ----------------
__global__ void frac_stats_kernel(const float* __restrict__ frac,
                                  float* __restrict__ fstats) {
  int wid = (int)((blockIdx.x * blockDim.x + threadIdx.x) >> 6);
  int ln = threadIdx.x & 63;
  if (wid >= 8192) return;
  int b = wid >> 10, q = wid & 1023;
  const float* fr = frac + b * 1024;
  float fq = fr[q];
  float sp = 0.f, sn = 0.f, sp2 = 0.f, sn2 = 0.f;
  for (int i = ln; i < 1024; i += 64) {
    float f = fr[i];
    float dm = (f - fq) * (fq * f);
    float p = fmaxf(dm, 0.f), nn = fminf(dm, 0.f);
    sp += p; sn += nn; sp2 += p * p; sn2 += nn * nn;
  }
  #pragma unroll
  for (int m = 32; m; m >>= 1) {
    sp += __shfl_xor(sp, m); sn += __shfl_xor(sn, m);
    sp2 += __shfl_xor(sp2, m); sn2 += __shfl_xor(sn2, m);
  }
  if (ln == 0) {
    float4 o; o.x = sp; o.y = sn; o.z = sp2; o.w = sn2;
    *(float4*)(fstats + (size_t)wid * 4) = o;
  }
}

// ---------------- fused QKV GEMM (proven v5) ----------------
__global__ __launch_bounds__(256) void qkv_gemm_kernel(
    const float* __restrict__ Aq, const float* __restrict__ Ak, const float* __restrict__ Av,
    const unsigned short* __restrict__ WqT, const unsigned short* __restrict__ WkT,
    const unsigned short* __restrict__ WvT,
    const float* __restrict__ bq, const float* __restrict__ bk, const float* __restrict__ bv,
    unsigned short* __restrict__ Qh, unsigned short* __restrict__ Kh,
    unsigned short* __restrict__ Vt) {
  __shared__ unsigned short Al[2][128 * 32];
  __shared__ unsigned short Bl[2][128 * 32];
  const int z = blockIdx.z;
  const float* A = z == 0 ? Aq : z == 1 ? Ak : Av;
  const unsigned short* Bt = z == 0 ? WqT : z == 1 ? WkT : WvT;
  const float* bias = z == 0 ? bq : z == 1 ? bk : bv;
  const float bscale = (z == 0) ? 0.125f : 1.0f;

  const int tid = threadIdx.x, ln = tid & 63, wv = tid >> 6;
  const int m0 = blockIdx.y * 128, n0 = blockIdx.x * 128;
  const int wr = wv >> 1, wc = wv & 1;
  const int arow = tid >> 1;
  const int agh = (tid & 1) * 2;

  auto stageB = [&](int kt, int buf) {
    int kb = kt * 32;
    #pragma unroll
    for (int u = 0; u < 2; ++u) {
      int n = tid + u * 256;
      int Lrow = n >> 2, kcs = n & 3;
      int kc = kcs ^ (Lrow & 3);
      GL16(Bt + (size_t)(n0 + Lrow) * 512 + kb + kc * 8, &Bl[buf][n * 8]);
    }
  };
  auto loadA = [&](int kt, float4* la) {
    const float* src = A + (size_t)(m0 + arow) * 512 + kt * 32 + agh * 8;
    la[0] = *(const float4*)(src);
    la[1] = *(const float4*)(src + 4);
    la[2] = *(const float4*)(src + 8);
    la[3] = *(const float4*)(src + 12);
  };
  auto writeA = [&](int buf, const float4* la) {
    #pragma unroll
    for (int G = 0; G < 2; ++G) {
      union { bf16x8 v; unsigned short u[8]; } pk;
      float4 a = la[2 * G], b2 = la[2 * G + 1];
      pk.u[0] = f2bf(a.x); pk.u[1] = f2bf(a.y); pk.u[2] = f2bf(a.z); pk.u[3] = f2bf(a.w);
      pk.u[4] = f2bf(b2.x); pk.u[5] = f2bf(b2.y); pk.u[6] = f2bf(b2.z); pk.u[7] = f2bf(b2.w);
      int dg = (agh + G) ^ (arow & 3);
      *(bf16x8*)(&Al[buf][arow * 32 + dg * 8]) = pk.v;
    }
  };

  f32x4 acc[4][4] = {};
  float4 la[4];
  loadA(0, la); writeA(0, la);
  stageB(0, 0);
  for (int kt = 0; kt < 16; ++kt) {
    __syncthreads();
    if (kt < 15) { loadA(kt + 1, la); stageB(kt + 1, (kt + 1) & 1); }
    const unsigned short* a_ = Al[kt & 1];
    const unsigned short* b_ = Bl[kt & 1];
    const int kc = ln >> 4;
    bf16x8 afr[4], bfr[4];
    #pragma unroll
    for (int m = 0; m < 4; ++m) {
      int r = wr * 64 + m * 16 + (ln & 15);
      afr[m] = *(const bf16x8*)(a_ + r * 32 + ((kc ^ (r & 3)) * 8));
    }
    #pragma unroll
    for (int n = 0; n < 4; ++n) {
      int r = wc * 64 + n * 16 + (ln & 15);
      bfr[n] = *(const bf16x8*)(b_ + r * 32 + ((kc ^ (r & 3)) * 8));
    }
    #pragma unroll
    for (int m = 0; m < 4; ++m)
      #pragma unroll
      for (int n = 0; n < 4; ++n)
        acc[m][n] = __builtin_amdgcn_mfma_f32_16x16x32_bf16(afr[m], bfr[n], acc[m][n], 0, 0, 0);
    if (kt < 15) writeA((kt + 1) & 1, la);
  }

  #pragma unroll
  for (int m = 0; m < 4; ++m) {
    #pragma unroll
    for (int n = 0; n < 4; ++n) {
      int gm0 = m0 + wr * 64 + m * 16 + (ln >> 4) * 4;
      int gn = n0 + wc * 64 + n * 16 + (ln & 15);
      float bvv = bias[gn] * bscale;
      int hh = gn >> 6, d = gn & 63;
      if (z < 2) {
        unsigned short* o = z == 0 ? Qh : Kh;
        #pragma unroll
        for (int i = 0; i < 4; ++i) {
          int gm = gm0 + i;
          int bb = gm >> 10, t = gm & 1023;
          o[(size_t)((bb * 8 + hh) * 1024 + t) * 64 + d] = f2bf(acc[m][n][i] + bvv);
        }
      } else {
        int bb = gm0 >> 10, t = gm0 & 1023;
        ushort4 pk;
        pk.x = f2bf(acc[m][n][0] + bvv);
        pk.y = f2bf(acc[m][n][1] + bvv);
        pk.z = f2bf(acc[m][n][2] + bvv);
        pk.w = f2bf(acc[m][n][3] + bvv);
        *(ushort4*)(Vt + (size_t)((bb * 8 + hh) * 64 + d) * 1024 + t) = pk;
      }
    }
  }
}

// ---------------- final GEMM (proven) ----------------
__global__ __launch_bounds__(256) void gemm_out_kernel(
    const unsigned short* __restrict__ A,
    const unsigned short* __restrict__ Bt,
    const float* __restrict__ bias,
    float* __restrict__ out) {
  __shared__ unsigned short Al[2][128 * 32];
  __shared__ unsigned short Bl[2][128 * 32];
  const int tid = threadIdx.x, ln = tid & 63, wv = tid >> 6;
  const int m0 = blockIdx.y * 128, n0 = blockIdx.x * 128;
  const int wr = wv >> 1, wc = wv & 1;

  auto stage = [&](int kt, int buf) {
    int kb = kt * 32;
    #pragma unroll
    for (int u = 0; u < 2; ++u) {
      int n = tid + u * 256;
      int Lrow = n >> 2, kcs = n & 3;
      int kc = kcs ^ (Lrow & 3);
      GL16(A + (size_t)(m0 + Lrow) * 512 + kb + kc * 8, &Al[buf][n * 8]);
      GL16(Bt + (size_t)(n0 + Lrow) * 512 + kb + kc * 8, &Bl[buf][n * 8]);
    }
  };

  f32x4 acc[4][4] = {};
  stage(0, 0);
  for (int kt = 0; kt < 16; ++kt) {
    __syncthreads();
    if (kt < 15) stage(kt + 1, (kt + 1) & 1);
    const unsigned short* a_ = Al[kt & 1];
    const unsigned short* b_ = Bl[kt & 1];
    const int kc = ln >> 4;
    bf16x8 afr[4], bfr[4];
    #pragma unroll
    for (int m = 0; m < 4; ++m) {
      int r = wr * 64 + m * 16 + (ln & 15);
      afr[m] = *(const bf16x8*)(a_ + r * 32 + ((kc ^ (r & 3)) * 8));
    }
    #pragma unroll
    for (int n = 0; n < 4; ++n) {
      int r = wc * 64 + n * 16 + (ln & 15);
      bfr[n] = *(const bf16x8*)(b_ + r * 32 + ((kc ^ (r & 3)) * 8));
    }
    #pragma unroll
    for (int m = 0; m < 4; ++m)
      #pragma unroll
      for (int n = 0; n < 4; ++n)
        acc[m][n] = __builtin_amdgcn_mfma_f32_16x16x32_bf16(afr[m], bfr[n], acc[m][n], 0, 0, 0);
  }
  #pragma unroll
  for (int m = 0; m < 4; ++m)
    #pragma unroll
    for (int n = 0; n < 4; ++n) {
      int gm0 = m0 + wr * 64 + m * 16 + (ln >> 4) * 4;
      int gn = n0 + wc * 64 + n * 16 + (ln & 15);
      float bvv = bias[gn];
      #pragma unroll
      for (int i = 0; i < 4; ++i)
        out[(size_t)(gm0 + i) * 512 + gn] = acc[m][n][i] + bvv;
    }
}

// ---------------- kernel A: S = Q K^T per (b,h), fp16 out + row partial stats ----------------
__global__ __launch_bounds__(256) void sgemm_kernel(
    const unsigned short* __restrict__ Qh,   // (b,h,t,d) bf16, pre-scaled
    const unsigned short* __restrict__ Kh,   // (b,h,t,d) bf16
    unsigned short* __restrict__ S,          // chunk: (bh_l, q, k) fp16
    float* __restrict__ gS, float* __restrict__ gS2,  // (bh, kt, q) partials
    int bh0) {
  __shared__ unsigned short Al[128 * 64];
  __shared__ unsigned short Bl[128 * 64];
  __shared__ float rSum[128];
  __shared__ float rSq[128];

  const int id = blockIdx.x;
  const int xcd = id & 7, slot = id >> 3;
  const int bh_l = xcd + 8 * (slot >> 6);
  const int tile = slot & 63;
  const int qt = tile >> 3, kt = tile & 7;
  const int bh = bh0 + bh_l;
  const int m0 = qt * 128, n0 = kt * 128;
  const int tid = threadIdx.x, ln = tid & 63, wv = tid >> 6;
  const int c = ln & 15, g = ln >> 4;
  const int wr = wv >> 1, wc = wv & 1;

  if (tid < 128) { rSum[tid] = 0.f; rSq[tid] = 0.f; }
  #pragma unroll
  for (int u = 0; u < 4; ++u) {
    int n = tid + u * 256;
    int row = n >> 3, kc = (n & 7) ^ (row & 7);
    GL16(Qh + (size_t)(bh * 1024 + m0 + row) * 64 + kc * 8, &Al[n * 8]);
  }
  #pragma unroll
  for (int u = 0; u < 4; ++u) {
    int n = tid + u * 256;
    int row = n >> 3, kc = (n & 7) ^ (row & 7);
    GL16(Kh + (size_t)(bh * 1024 + n0 + row) * 64 + kc * 8, &Bl[n * 8]);
  }
  __syncthreads();

  f32x4 acc[4][4] = {};
  #pragma unroll
  for (int ks = 0; ks < 2; ++ks) {
    bf16x8 afr[4], bfr[4];
    #pragma unroll
    for (int m = 0; m < 4; ++m) {
      int r = wr * 64 + m * 16 + c;
      afr[m] = *(const bf16x8*)(&Al[r * 64 + (((g + ks * 4) ^ (r & 7)) * 8)]);
    }
    #pragma unroll
    for (int n = 0; n < 4; ++n) {
      int r = wc * 64 + n * 16 + c;
      bfr[n] = *(const bf16x8*)(&Bl[r * 64 + (((g + ks * 4) ^ (r & 7)) * 8)]);
    }
    #pragma unroll
    for (int m = 0; m < 4; ++m)
      #pragma unroll
      for (int n = 0; n < 4; ++n)
        acc[m][n] = __builtin_amdgcn_mfma_f32_16x16x32_bf16(afr[m], bfr[n], acc[m][n], 0, 0, 0);
  }

  // S store (fp16) + row stats
  #pragma unroll
  for (int m = 0; m < 4; ++m) {
    #pragma unroll
    for (int i = 0; i < 4; ++i) {
      int q = m0 + wr * 64 + m * 16 + g * 4 + i;
      float s_ = 0.f, q_ = 0.f;
      #pragma unroll
      for (int n = 0; n < 4; ++n) {
        float v = acc[m][n][i];
        s_ += v; q_ += v * v;
        int k = n0 + wc * 64 + n * 16 + c;
        union { _Float16 h; unsigned short u; } cv;
        cv.h = (_Float16)v;
        S[(size_t)(bh_l * 1024 + q) * 1024 + k] = cv.u;
      }
      #pragma unroll
      for (int msk = 1; msk < 16; msk <<= 1) {
        s_ += __shfl_xor(s_, msk);
        q_ += __shfl_xor(q_, msk);
      }
      if (c == 0) {
        atomicAdd(&rSum[wr * 64 + m * 16 + g * 4 + i], s_);
        atomicAdd(&rSq[wr * 64 + m * 16 + g * 4 + i], q_);
      }
    }
  }
  __syncthreads();
  if (tid < 128) {
    gS[(size_t)(bh * 8 + kt) * 1024 + m0 + tid] = rSum[tid];
    gS2[(size_t)(bh * 8 + kt) * 1024 + m0 + tid] = rSq[tid];
  }
}

// ---------------- kernel B: transform + exp2 + PV ----------------
__global__ __launch_bounds__(256) void pv_kernel(
    const unsigned short* __restrict__ S,    // chunk fp16
    const unsigned short* __restrict__ Vt,   // (b,h,d,t) bf16
    unsigned short* __restrict__ attnO,      // (b,t,h*64+d) bf16
    const float* __restrict__ frac,
    const float* __restrict__ fstats,
    const float* __restrict__ gS, const float* __restrict__ gS2,
    const float* __restrict__ alpha_pos, const float* __restrict__ alpha_neg,
    const float* __restrict__ gamma_p, const float* __restrict__ delta_p,
    const int* __restrict__ afb_p, int bh0) {
  __shared__ float Obuf[32][65];
  __shared__ float fk[1024];
  __shared__ float4 rowc[32];
  __shared__ float rowSh[32];
  __shared__ float sumP[4][32];
  __shared__ float rowRcp[32];

  const int id = blockIdx.x;
  const int xcd = id & 7, slot = id >> 3;
  const int bh_l = xcd + 8 * (slot >> 5);
  const int t0 = (slot & 31) * 32;
  const int bh = bh0 + bh_l;
  const int b = bh >> 3, h = bh & 7;
  const int tid = threadIdx.x, ln = tid & 63, w = tid >> 6;
  const int c = ln & 15, g = ln >> 4;

  {
    float* ob = &Obuf[0][0];
    for (int i = tid; i < 32 * 65; i += 256) ob[i] = 0.f;
    fk[tid] = frac[b * 1024 + tid];
    fk[tid + 256] = frac[b * 1024 + 256 + tid];
    fk[tid + 512] = frac[b * 1024 + 512 + tid];
    fk[tid + 768] = frac[b * 1024 + 768 + tid];
  }
  if (tid < 32) {
    int q = t0 + tid;
    float sl = 0.f, sl2 = 0.f;
    #pragma unroll
    for (int j = 0; j < 8; ++j) {
      sl += gS[(size_t)(bh * 8 + j) * 1024 + q];
      sl2 += gS2[(size_t)(bh * 8 + j) * 1024 + q];
    }
    float mul_ = sl * (1.f / 1024.f);
    float varl = fmaxf((sl2 - 1024.f * mul_ * mul_) * (1.f / 1023.f), 0.f);
    float cA = (*gamma_p) / (sqrtf(varl) + EPS);
    float ap = alpha_pos[h], an = alpha_neg[h];
    float4 st = *(const float4*)(fstats + (size_t)(b * 1024 + q) * 4);
    float msum = ap * st.x + an * st.y;
    float msq = ap * ap * st.z + an * an * st.w;
    float mus = msum * (1.f / 1024.f);
    float vars = fmaxf((msq - 1024.f * mus * mus) * (1.f / 1023.f), 0.f);
    float cB = (*afb_p) ? ((*delta_p) / (sqrtf(vars) + EPS)) : 0.f;
    const float L2E = 1.4426950408889634f;
    float a_ = 0.5f * (ap + an), c_ = 0.5f * (ap - an);
    float4 rc;
    rc.x = frac[b * 1024 + q];
    rc.y = cA * L2E;
    rc.z = cB * a_ * L2E;
    rc.w = cB * c_ * L2E;
    rowc[tid] = rc;
    rowSh[tid] = (cA * mul_ + cB * mus) * L2E;
  }
  __syncthreads();

  const int k0 = w * 256;
  f32x4 acc[2][4] = {};
  float ps0 = 0.f, ps1 = 0.f;
  const float4 rc0 = rowc[c], rc1 = rowc[16 + c];
  const float sh0 = rowSh[c], sh1 = rowSh[16 + c];

  #pragma unroll
  for (int kt = 0; kt < 8; ++kt) {
    const int kk = k0 + kt * 32 + g * 8;
    bf16x8 vf[4];
    #pragma unroll
    for (int dt = 0; dt < 4; ++dt)
      vf[dt] = *(const bf16x8*)(Vt + (size_t)(bh * 64 + dt * 16 + c) * 1024 + kk);
    float frv[8];
    #pragma unroll
    for (int ee = 0; ee < 8; ++ee) frv[ee] = fk[kk + ee];

    #pragma unroll
    for (int qtt = 0; qtt < 2; ++qtt) {
      const float4 rc = qtt ? rc1 : rc0;
      const float sh = qtt ? sh1 : sh0;
      const int q = t0 + qtt * 16 + c;
      bf16x8 sv = *(const bf16x8*)(S + (size_t)(bh_l * 1024 + q) * 1024 + kk);
      float e[8];
      float psl = 0.f;
      #pragma unroll
      for (int ee = 0; ee < 8; ++ee) {
        union { unsigned short u; _Float16 h; } cv;
        cv.u = (unsigned short)sv[ee];
        float sval = (float)cv.h;
        float f = frv[ee];
        float tt = f * rc.x, d = f - rc.x;
        float x = tt * d, ax = tt * __builtin_fabsf(d);
        float arg = rc.y * sval + rc.z * x + rc.w * ax - sh;
        float ev = __builtin_amdgcn_exp2f(arg);
        e[ee] = ev; psl += ev;
      }
      if (qtt == 0) ps0 += psl; else ps1 += psl;
      union { unsigned u[4]; bf16x8 v; } pa;
      #pragma unroll
      for (int jj = 0; jj < 4; ++jj) {
        unsigned u0 = __float_as_uint(e[2 * jj]);
        unsigned u1 = __float_as_uint(e[2 * jj + 1]);
        pa.u[jj] = ((u1 + 0x8000u) & 0xFFFF0000u) | ((u0 + 0x8000u) >> 16);
      }
      #pragma unroll
      for (int dt = 0; dt < 4; ++dt)
        acc[qtt][dt] = __builtin_amdgcn_mfma_f32_16x16x32_bf16(pa.v, vf[dt], acc[qtt][dt], 0, 0, 0);
    }
  }

  ps0 += __shfl_xor(ps0, 16); ps0 += __shfl_xor(ps0, 32);
  ps1 += __shfl_xor(ps1, 16); ps1 += __shfl_xor(ps1, 32);
  if (g == 0) { sumP[w][c] = ps0; sumP[w][16 + c] = ps1; }

  #pragma unroll
  for (int qtt = 0; qtt < 2; ++qtt)
    #pragma unroll
    for (int dt = 0; dt < 4; ++dt)
      #pragma unroll
      for (int i = 0; i < 4; ++i)
        atomicAdd(&Obuf[qtt * 16 + g * 4 + i][dt * 16 + c], acc[qtt][dt][i]);

  __syncthreads();
  if (tid < 32)
    rowRcp[tid] = 1.f / (sumP[0][tid] + sumP[1][tid] + sumP[2][tid] + sumP[3][tid]);
  __syncthreads();

  {
    int q = tid >> 3, d0 = (tid & 7) * 8;
    float rcp = rowRcp[q];
    union { bf16x8 v; unsigned short u[8]; } o8;
    #pragma unroll
    for (int j = 0; j < 8; ++j) o8.u[j] = f2bf(Obuf[q][d0 + j] * rcp);
    *(bf16x8*)(attnO + (size_t)(b * 1024 + t0 + q) * 512 + h * 64 + d0) = o8.v;
  }
}

extern "C" void kernel_launch(void* const* d_in, const int* in_sizes, int n_in,
                              void* d_out, int out_size, void* d_ws, size_t ws_size,
                              hipStream_t stream) {
  const float* q = (const float*)d_in[0];
  const float* k = (const float*)d_in[1];
  const float* v = (const float*)d_in[2];
  const float* frac = (const float*)d_in[3];
  const float* Wq = (const float*)d_in[4];
  const float* bq = (const float*)d_in[5];
  const float* Wk = (const float*)d_in[6];
  const float* bk = (const float*)d_in[7];
  const float* Wv = (const float*)d_in[8];
  const float* bv = (const float*)d_in[9];
  const float* Wo = (const float*)d_in[10];
  const float* bo = (const float*)d_in[11];
  const float* ap = (const float*)d_in[12];
  const float* an = (const float*)d_in[13];
  const float* gm = (const float*)d_in[14];
  const float* dl = (const float*)d_in[15];
  const int* afb = (const int*)d_in[16];

  char* ws = (char*)d_ws;
  unsigned short* wqT = (unsigned short*)(ws + 0);
  unsigned short* wkT = (unsigned short*)(ws + 524288);
  unsigned short* wvT = (unsigned short*)(ws + 1048576);
  unsigned short* woT = (unsigned short*)(ws + 1572864);
  unsigned short* Qh = (unsigned short*)(ws + 2097152);
  unsigned short* Kh = (unsigned short*)(ws + 10485760);
  unsigned short* Vt = (unsigned short*)(ws + 18874368);
  unsigned short* aO = (unsigned short*)(ws + 27262976);
  float* fst = (float*)(ws + 35651584);
  float* gS = (float*)(ws + 35782656);
  float* gS2 = (float*)(ws + 37879808);
  unsigned short* S = (unsigned short*)(ws + 39976960);

  // chunk size (bh per pass) based on available scratch for S (2 MB per bh)
  size_t avail = ws_size > 39976960 ? ws_size - 39976960 : 0;
  int CH = 8;
  if (avail >= (size_t)64 * 2097152) CH = 64;
  else if (avail >= (size_t)32 * 2097152) CH = 32;
  else if (avail >= (size_t)16 * 2097152) CH = 16;

  wtrans4_kernel<<<dim3(16, 16, 4), 256, 0, stream>>>(Wq, Wk, Wv, Wo, wqT, wkT, wvT, woT);
  frac_stats_kernel<<<2048, 256, 0, stream>>>(frac, fst);
  qkv_gemm_kernel<<<dim3(4, 64, 3), 256, 0, stream>>>(q, k, v, wqT, wkT, wvT,
                                                      bq, bk, bv, Qh, Kh, Vt);
  for (int bh0 = 0; bh0 < 64; bh0 += CH) {
    sgemm_kernel<<<CH * 64, 256, 0, stream>>>(Qh, Kh, S, gS, gS2, bh0);
    pv_kernel<<<CH * 32, 256, 0, stream>>>(S, Vt, aO, frac, fst, gS, gS2,
                                           ap, an, gm, dl, afb, bh0);
  }
  gemm_out_kernel<<<dim3(4, 64), 256, 0, stream>>>(aO, woT, bo, (float*)d_out);
}